// Round 1
// baseline (152.755 us; speedup 1.0000x reference)
//
#include <hip/hip_runtime.h>
#include <hip/hip_bf16.h>

#define BB 4
#define TT 256
#define LL 128
#define EE 64
#define SCALE 0.125f  // 1/sqrt(64)

// K1: dotT[b][t][l] = <harmony[b,l,:], note[b,t,:]>
// grid = B*T blocks, 128 threads (= l)
__global__ __launch_bounds__(128) void k_dot(const float* __restrict__ note,
                                             const float* __restrict__ harm,
                                             float* __restrict__ dotT) {
    int bt = blockIdx.x;
    int b = bt >> 8;          // T=256
    int t = bt & 255;
    int l = threadIdx.x;

    __shared__ float n[EE];
    if (threadIdx.x < EE) n[threadIdx.x] = note[(b * TT + t) * EE + threadIdx.x];
    __syncthreads();

    const float* h = harm + (b * LL + l) * EE;
    float acc = 0.f;
#pragma unroll
    for (int e = 0; e < EE; e += 4) {
        float4 hv = *(const float4*)(h + e);
        acc += hv.x * n[e] + hv.y * n[e + 1] + hv.z * n[e + 2] + hv.w * n[e + 3];
    }
    dotT[(b * TT + t) * LL + l] = acc;
}

// K2: MT[b][l][s] = max_{t>=s} dotT[b][t][l]*SCALE  (reverse inclusive max-scan)
// grid = B*L blocks, 256 threads (= t)
__global__ __launch_bounds__(256) void k_sufmax(const float* __restrict__ dotT,
                                                float* __restrict__ MT) {
    int bl = blockIdx.x;
    int b = bl >> 7;          // L=128
    int l = bl & 127;
    int t = threadIdx.x;

    __shared__ float sm[TT];
    sm[t] = dotT[(b * TT + t) * LL + l] * SCALE;
    __syncthreads();

#pragma unroll
    for (int off = 1; off < TT; off <<= 1) {
        float v = sm[t];
        float o = (t + off < TT) ? sm[t + off] : -3.402823466e38f;
        __syncthreads();
        sm[t] = fmaxf(v, o);
        __syncthreads();
    }
    MT[(b * LL + l) * TT + t] = sm[t];
}

// K3: main scan. grid = B*T/2 blocks of 256 threads; each half-block (2 waves)
// handles one s, lanes = l. out[b][s][e][l].
__global__ __launch_bounds__(256) void k_main(const float* __restrict__ dotT,
                                              const float* __restrict__ MT,
                                              float* __restrict__ out) {
    int blk = blockIdx.x;         // 0 .. B*T/2-1
    int b = blk >> 7;             // 128 s-pairs per b
    int sp = blk & 127;
    int s = sp * 2 + (threadIdx.x >> 7);
    int l = threadIdx.x & 127;

    float m = MT[(b * LL + l) * TT + s];
    const float* dp = dotT + b * TT * LL + l;
    float* op = out + (size_t)((b * TT + s) * TT) * LL + l;

    // e < s: zeros (harness poisons d_out; lower triangle must be 0)
#pragma unroll 8
    for (int e = 0; e < s; ++e) op[e * LL] = 0.f;

    float denom = 0.f, numer = 0.f;
#pragma unroll 4
    for (int e = s; e < TT; ++e) {
        float d = dp[e * LL];
        float ex = __expf(d * SCALE - m);
        denom += ex;
        numer += ex * d;
        op[e * LL] = numer / fmaxf(denom, 1e-30f);
    }
}

extern "C" void kernel_launch(void* const* d_in, const int* in_sizes, int n_in,
                              void* d_out, int out_size, void* d_ws, size_t ws_size,
                              hipStream_t stream) {
    const float* note = (const float*)d_in[0];   // [B,T,E]
    const float* harm = (const float*)d_in[1];   // [B,L,E]
    float* out = (float*)d_out;                  // [B,T,T,L]

    float* dotT = (float*)d_ws;                  // [B,T,L] = 512 KB
    float* MT = dotT + BB * TT * LL;             // [B,L,T] = 512 KB

    k_dot<<<BB * TT, 128, 0, stream>>>(note, harm, dotT);
    k_sufmax<<<BB * LL, 256, 0, stream>>>(dotT, MT);
    k_main<<<BB * TT / 2, 256, 0, stream>>>(dotT, MT, out);
}